// Round 11
// baseline (728.976 us; speedup 1.0000x reference)
//
#include <hip/hip_runtime.h>
#include <hip/hip_fp16.h>
#include <math.h>

#define N_NODES   100000
#define N_EDGES   1600000
#define NDIM      64
#define H         128
#define NUM_LAYERS 3
#define NUM_CLASSES 6
#define NUM_GRAPHS 512
#define LN_EPS    1e-5f
#define NBKT      391           // ceil(N_NODES / 256)
#define SCAP      5376          // phase-B LDS col capacity
#define BPAD      136           // gate kernel LDS row stride (halves)
#define APAD      136           // fused kernel A/out staging row stride (halves)
#define BPAD2     72            // fused kernel B row stride per 64-k chunk (halves)

typedef _Float16 f16x8 __attribute__((ext_vector_type(8)));
typedef float    f32x4 __attribute__((ext_vector_type(4)));

// ---------- helpers ----------
__device__ __forceinline__ int idx_at(const int* raw, int is64, int i) {
    return is64 ? raw[2 * (long long)i] : raw[i];
}
__device__ __forceinline__ int lower_bound(const int* a, int n, int v) {
    int lo = 0, hi = n;
    while (lo < hi) { int m = (lo + hi) >> 1; if (a[m] < v) lo = m + 1; else hi = m; }
    return lo;
}

// ---------- dtype detection ----------
__global__ void k_detect(const int* eraw, const int* braw, int* flags) {
    if (threadIdx.x == 0 && blockIdx.x == 0) {
        int e64 = 1;
        for (int i = 1; i < 128; i += 2) if (eraw[i] != 0) { e64 = 0; break; }
        flags[0] = e64;
        flags[1] = (braw[N_NODES - 1] == 0) ? 1 : 0;
    }
}

// ---------- init ----------
__global__ void k_init(int* bcnt) {
    int i = blockIdx.x * blockDim.x + threadIdx.x;
    if (i < 512) bcnt[i] = 0;
}

__global__ void k_conv_batch(const int* braw, const int* flags, int* batch32) {
    int i = blockIdx.x * blockDim.x + threadIdx.x;
    if (i < N_NODES) batch32[i] = idx_at(braw, flags[1], i);
}

// ---------- bucket histogram ----------
__global__ __launch_bounds__(256) void k_bhist(const int* eraw, const int* flags, int* bcnt) {
    __shared__ int c[512];
    int tid = threadIdx.x;
    for (int i = tid; i < 512; i += 256) c[i] = 0;
    __syncthreads();
    int f = flags[0];
    int stride = gridDim.x * 256;
    for (int e = blockIdx.x * 256 + tid; e < N_EDGES; e += stride) {
        int d = idx_at(eraw, f, N_EDGES + e);
        atomicAdd(&c[d >> 8], 1);
    }
    __syncthreads();
    for (int i = tid; i < 512; i += 256) if (c[i]) atomicAdd(&bcnt[i], c[i]);
}

// ---------- scan of 512 bucket counts ----------
__global__ void k_bscan(const int* bcnt, int* boff, int* bcursor) {
    __shared__ int sh[512];
    int tid = threadIdx.x;
    int v = bcnt[tid];
    sh[tid] = v;
    __syncthreads();
    for (int off = 1; off < 512; off <<= 1) {
        int u = (tid >= off) ? sh[tid - off] : 0;
        __syncthreads();
        sh[tid] += u;
        __syncthreads();
    }
    int excl = sh[tid] - v;
    boff[tid] = excl;
    bcursor[tid] = excl;
    if (tid == 511) boff[512] = sh[511];
}

// ---------- phase A bucket scatter ----------
#define EPB 4096
__global__ __launch_bounds__(256) void k_bucket(const int* eraw, const int* flags,
                                                int* bcursor, unsigned int* br) {
    __shared__ int cnt[512];
    __shared__ int lcur[512];
    int tid = threadIdx.x;
    int f = flags[0];
    int base = blockIdx.x * EPB;
    int se[16], de[16];
#pragma unroll
    for (int j = 0; j < 16; ++j) {
        int e = base + j * 256 + tid;
        if (e < N_EDGES) {
            se[j] = idx_at(eraw, f, e);
            de[j] = idx_at(eraw, f, N_EDGES + e);
        } else de[j] = -1;
    }
    for (int i = tid; i < 512; i += 256) cnt[i] = 0;
    __syncthreads();
#pragma unroll
    for (int j = 0; j < 16; ++j)
        if (de[j] >= 0) atomicAdd(&cnt[de[j] >> 8], 1);
    __syncthreads();
    for (int i = tid; i < 512; i += 256)
        lcur[i] = cnt[i] ? atomicAdd(&bcursor[i], cnt[i]) : 0;
    __syncthreads();
#pragma unroll
    for (int j = 0; j < 16; ++j)
        if (de[j] >= 0) {
            int pos = atomicAdd(&lcur[de[j] >> 8], 1);
            br[pos] = ((unsigned int)(de[j] & 255) << 24) | (unsigned int)se[j];
        }
}

// ---------- per-bucket degree count ----------
__global__ __launch_bounds__(256) void k_bdeg(const unsigned int* br, const int* boff, int* deg) {
    __shared__ int d256[256];
    int b = blockIdx.x;
    int tid = threadIdx.x;
    d256[tid] = 0;
    __syncthreads();
    int lo = boff[b], hi = boff[b + 1];
    for (int i = lo + tid; i < hi; i += 256)
        atomicAdd(&d256[br[i] >> 24], 1);
    __syncthreads();
    int node = (b << 8) + tid;
    if (node < N_NODES) deg[node] = d256[tid];
}

// ---------- scans over deg -> rowptr ----------
__global__ void k_scan1(const int* deg, int* rowptr, int* bsums) {
    __shared__ int sh[256];
    int tid = threadIdx.x;
    int i0 = blockIdx.x * 512 + tid * 2;
    int a = (i0 < N_NODES) ? deg[i0] : 0;
    int b = (i0 + 1 < N_NODES) ? deg[i0 + 1] : 0;
    int ts = a + b;
    sh[tid] = ts;
    __syncthreads();
    for (int off = 1; off < 256; off <<= 1) {
        int v = (tid >= off) ? sh[tid - off] : 0;
        __syncthreads();
        sh[tid] += v;
        __syncthreads();
    }
    int excl = sh[tid] - ts;
    if (i0 < N_NODES) rowptr[i0] = excl;
    if (i0 + 1 < N_NODES) rowptr[i0 + 1] = excl + a;
    if (tid == 255) bsums[blockIdx.x] = sh[255];
}

__global__ void k_scan2(int* bsums, int nb) {
    __shared__ int sh[256];
    int tid = threadIdx.x;
    int v = (tid < nb) ? bsums[tid] : 0;
    sh[tid] = v;
    __syncthreads();
    for (int off = 1; off < 256; off <<= 1) {
        int u = (tid >= off) ? sh[tid - off] : 0;
        __syncthreads();
        sh[tid] += u;
        __syncthreads();
    }
    if (tid < nb) bsums[tid] = sh[tid] - v;
}

__global__ void k_scan3(int* rowptr, const int* bsums, int* cursor) {
    int i = blockIdx.x * blockDim.x + threadIdx.x;
    if (i < N_NODES) {
        int r = rowptr[i] + bsums[i >> 9];
        rowptr[i] = r;
        cursor[i] = r;
    }
    if (i == 0) rowptr[N_NODES] = N_EDGES;
}

// ---------- phase B: col stores BYTE OFFSETS (src*256) ----------
__global__ __launch_bounds__(256) void k_scatter2(const unsigned int* br, const int* boff,
                                                  const int* rowptr, int* cursor, int* col) {
    __shared__ int lcur[256];
    __shared__ int cbuf[SCAP];
    int b = blockIdx.x;
    int tid = threadIdx.x;
    int lo = boff[b], hi = boff[b + 1];
    int wsize = hi - lo;
    int node = (b << 8) + tid;
    lcur[tid] = rowptr[node < N_NODES ? node : N_NODES] - lo;
    __syncthreads();
    if (wsize <= SCAP) {
        for (int i = lo + tid; i < hi; i += 256) {
            unsigned int r = br[i];
            int p = atomicAdd(&lcur[r >> 24], 1);
            cbuf[p] = (int)(r & 0xFFFFFF);
        }
        __syncthreads();
        for (int j = tid; j < wsize; j += 256) col[lo + j] = cbuf[j] << 8;
    } else {
        for (int i = lo + tid; i < hi; i += 256) {
            unsigned int r = br[i];
            int d = (b << 8) + (int)(r >> 24);
            int p = atomicAdd(&cursor[d], 1);
            col[p] = (int)(r & 0xFFFFFF) << 8;
        }
    }
}

// ---------- weight prep ----------
__global__ void k_prepw(const float* __restrict__ lin_l_w, const float* __restrict__ lin_r_w,
                        const float* __restrict__ gate_w1,
                        __half* __restrict__ W16t, __half* __restrict__ W16g) {
    int i = blockIdx.x * 256 + threadIdx.x;
    if (i < NUM_LAYERS * 128 * 256) {
        int l = i >> 15;
        int rem = i & 32767;
        int n = rem >> 8;
        int k = rem & 255;
        float v = (k < 128) ? lin_l_w[(size_t)l * 16384 + k * 128 + n]
                            : lin_r_w[(size_t)l * 16384 + (k - 128) * 128 + n];
        W16t[(size_t)l * 32768 + n * 256 + k] = __float2half(v);
    } else if (i < NUM_LAYERS * 128 * 256 + 64 * 128) {
        int idx = i - NUM_LAYERS * 128 * 256;
        int n = idx >> 7;
        int k = idx & 127;
        W16g[n * 128 + k] = __float2half(gate_w1[k * 64 + n]);
    }
}

// ---------- tiled fp32 GEMM (COLS=128): h16 = fp16(relu(A[n,K] @ W + bias)) ----------
__global__ __launch_bounds__(256) void k_gemm_proj(const float* __restrict__ A,
                                                   const float* __restrict__ W,
                                                   const float* __restrict__ bias,
                                                   __half* __restrict__ C16,
                                                   int nrows, int K) {
    __shared__ float As_t[32][68];
    __shared__ float Ws[32 * 128];
    int tid = threadIdx.x;
    int row0 = blockIdx.x * 64;
    int tr = tid >> 4;
    int tc = tid & 15;
    int c0 = tc * 8;
    float acc[4][8];
#pragma unroll
    for (int i = 0; i < 4; ++i)
#pragma unroll
        for (int j = 0; j < 8; ++j) acc[i][j] = 0.f;

    for (int kc = 0; kc < K; kc += 32) {
        __syncthreads();
#pragma unroll
        for (int it = 0; it < 2; ++it) {
            int idx = tid + it * 256;
            int r = idx >> 3, c4 = idx & 7;
            int gr = row0 + r;
            float4 v = make_float4(0.f, 0.f, 0.f, 0.f);
            if (gr < nrows) v = *(const float4*)(A + (size_t)gr * K + kc + c4 * 4);
            As_t[c4 * 4 + 0][r] = v.x;
            As_t[c4 * 4 + 1][r] = v.y;
            As_t[c4 * 4 + 2][r] = v.z;
            As_t[c4 * 4 + 3][r] = v.w;
        }
#pragma unroll
        for (int it = 0; it < 4; ++it) {
            int idx = tid + it * 256;
            int r = idx >> 5, c4 = idx & 31;
            *(float4*)(&Ws[r * 128 + c4 * 4]) = *(const float4*)(W + (size_t)(kc + r) * 128 + c4 * 4);
        }
        __syncthreads();
#pragma unroll
        for (int k = 0; k < 32; ++k) {
            float4 a4 = *(const float4*)(&As_t[k][tr * 4]);
            float a[4] = {a4.x, a4.y, a4.z, a4.w};
            float4 w0 = *(const float4*)(&Ws[k * 128 + c0]);
            float4 w1 = *(const float4*)(&Ws[k * 128 + c0 + 4]);
            float w[8] = {w0.x, w0.y, w0.z, w0.w, w1.x, w1.y, w1.z, w1.w};
#pragma unroll
            for (int i = 0; i < 4; ++i)
#pragma unroll
                for (int j = 0; j < 8; ++j) acc[i][j] += a[i] * w[j];
        }
    }
    float bv[8];
#pragma unroll
    for (int j = 0; j < 8; ++j) bv[j] = bias[c0 + j];
#pragma unroll
    for (int i = 0; i < 4; ++i) {
        int gr = row0 + tr * 4 + i;
        if (gr < nrows) {
            float o[8];
#pragma unroll
            for (int j = 0; j < 8; ++j) o[j] = fmaxf(acc[i][j] + bv[j], 0.f);
            __half2 p[4];
#pragma unroll
            for (int j = 0; j < 8; j += 2) p[j / 2] = __floats2half2_rn(o[j], o[j + 1]);
            *(float4*)(C16 + (size_t)gr * 128 + c0) = *(float4*)p;
        }
    }
}

// ---------- FUSED aggr + SAGE layer (ping-pong: reads hin only, writes hout only) ----------
// Per block: 64 nodes. Phase 0: gather-mean neighbor rows (from hin) into LDS As.
// Phase 1: [As | hin] @ [Wl;Wr] via MFMA (B in 64-k LDS chunks), LN+ELU+residual(hin),
// staged epilogue -> hout. No block reads hout => no inter-block race.
__global__ __launch_bounds__(256) void k_aggr_layer(const __half* __restrict__ hin,
                                                    __half* __restrict__ hout,
                                                    const int* __restrict__ rowptr,
                                                    const int* __restrict__ col,
                                                    const __half* __restrict__ W16t,
                                                    const float* __restrict__ bl,
                                                    const float* __restrict__ g,
                                                    const float* __restrict__ bb) {
    __shared__ __half As[64 * APAD];    // aggregated rows, later output staging
    __shared__ __half Bs[128 * BPAD2];  // weight chunk
    int tid = threadIdx.x;
    int wave = tid >> 6, lane = tid & 63;
    int li = lane & 31, pg = lane >> 5;
    int s = lane & 15, quad = lane >> 4;
    int row0 = blockIdx.x * 64;

    // ---- phase 0: gather-mean 16 nodes per wave into As (reads hin) ----
    const char* hbase = (const char*)hin + li * 8;
    for (int j = 0; j < 16; ++j) {
        int node = row0 + wave * 16 + j;
        int e0 = 0, e1 = 0;
        if (node < N_NODES) { e0 = rowptr[node]; e1 = rowptr[node + 1]; }
        __half2 z = __floats2half2_rn(0.f, 0.f);
        __half2 a0 = z, a1 = z, b0 = z, b1 = z, c0 = z, c1 = z, d0 = z, d1 = z;
        int e = e0;
        for (; e + 7 < e1; e += 8) {
            float2 rA = *(const float2*)(hbase + col[e + pg]);
            float2 rB = *(const float2*)(hbase + col[e + 2 + pg]);
            float2 rC = *(const float2*)(hbase + col[e + 4 + pg]);
            float2 rD = *(const float2*)(hbase + col[e + 6 + pg]);
            const __half2* hA = (const __half2*)&rA;
            const __half2* hB = (const __half2*)&rB;
            const __half2* hC = (const __half2*)&rC;
            const __half2* hD = (const __half2*)&rD;
            a0 = __hadd2(a0, hA[0]); a1 = __hadd2(a1, hA[1]);
            b0 = __hadd2(b0, hB[0]); b1 = __hadd2(b1, hB[1]);
            c0 = __hadd2(c0, hC[0]); c1 = __hadd2(c1, hC[1]);
            d0 = __hadd2(d0, hD[0]); d1 = __hadd2(d1, hD[1]);
        }
        for (; e + 3 < e1; e += 4) {
            float2 rA = *(const float2*)(hbase + col[e + pg]);
            float2 rB = *(const float2*)(hbase + col[e + 2 + pg]);
            const __half2* hA = (const __half2*)&rA;
            const __half2* hB = (const __half2*)&rB;
            a0 = __hadd2(a0, hA[0]); a1 = __hadd2(a1, hA[1]);
            b0 = __hadd2(b0, hB[0]); b1 = __hadd2(b1, hB[1]);
        }
        for (; e + 1 < e1; e += 2) {
            float2 rA = *(const float2*)(hbase + col[e + pg]);
            const __half2* hA = (const __half2*)&rA;
            a0 = __hadd2(a0, hA[0]); a1 = __hadd2(a1, hA[1]);
        }
        if (e < e1 && pg == 0) {
            float2 rA = *(const float2*)(hbase + col[e]);
            const __half2* hA = (const __half2*)&rA;
            a0 = __hadd2(a0, hA[0]); a1 = __hadd2(a1, hA[1]);
        }
        float2 fa0 = __half22float2(a0), fb0 = __half22float2(b0);
        float2 fc0 = __half22float2(c0), fd0 = __half22float2(d0);
        float2 fa1 = __half22float2(a1), fb1 = __half22float2(b1);
        float2 fc1 = __half22float2(c1), fd1 = __half22float2(d1);
        float s0 = fa0.x + fb0.x + fc0.x + fd0.x;
        float s1 = fa0.y + fb0.y + fc0.y + fd0.y;
        float s2 = fa1.x + fb1.x + fc1.x + fd1.x;
        float s3 = fa1.y + fb1.y + fc1.y + fd1.y;
        s0 += __shfl_xor(s0, 32);
        s1 += __shfl_xor(s1, 32);
        s2 += __shfl_xor(s2, 32);
        s3 += __shfl_xor(s3, 32);
        if (pg == 0) {
            int d = e1 - e0;
            float inv = 1.0f / (float)(d > 1 ? d : 1);
            __half2 h01 = __floats2half2_rn(s0 * inv, s1 * inv);
            __half2 h23 = __floats2half2_rn(s2 * inv, s3 * inv);
            float2 o;
            ((__half2*)&o)[0] = h01;
            ((__half2*)&o)[1] = h23;
            *(float2*)(&As[(wave * 16 + j) * APAD + li * 4]) = o;
        }
    }

    // ---- phase 1: MFMA over K=256 in four 64-k chunks ----
    int arow = row0 + wave * 16 + s;
    if (arow >= N_NODES) arow = N_NODES - 1;
    f32x4 acc[8];
#pragma unroll
    for (int c = 0; c < 8; ++c) acc[c] = (f32x4){0.f, 0.f, 0.f, 0.f};

#pragma unroll
    for (int c4 = 0; c4 < 4; ++c4) {
        __syncthreads();
#pragma unroll
        for (int it = 0; it < 4; ++it) {
            int idx = tid + it * 256;
            int n = idx >> 3, f4 = idx & 7;
            *(float4*)(&Bs[n * BPAD2 + f4 * 8]) =
                *(const float4*)(W16t + (size_t)n * 256 + c4 * 64 + f4 * 8);
        }
        __syncthreads();
#pragma unroll
        for (int kk = 0; kk < 64; kk += 32) {
            f16x8 afrag;
            if (c4 < 2)
                afrag = *(const f16x8*)(&As[(wave * 16 + s) * APAD + c4 * 64 + kk + quad * 8]);
            else
                afrag = *(const f16x8*)(hin + (size_t)arow * H + (c4 - 2) * 64 + kk + quad * 8);
#pragma unroll
            for (int c = 0; c < 8; ++c) {
                f16x8 bfrag = *(const f16x8*)(&Bs[(c * 16 + s) * BPAD2 + kk + quad * 8]);
                acc[c] = __builtin_amdgcn_mfma_f32_16x16x32_f16(afrag, bfrag, acc[c], 0, 0, 0);
            }
        }
    }

    // ---- epilogue: bias + LN + ELU, staged to As, coalesced residual(hin)+write(hout) ----
    float y[8][4];
    float sm[4] = {0.f, 0.f, 0.f, 0.f}, sq[4] = {0.f, 0.f, 0.f, 0.f};
#pragma unroll
    for (int c = 0; c < 8; ++c) {
        float bv = bl[c * 16 + s];
#pragma unroll
        for (int i = 0; i < 4; ++i) {
            float v = acc[c][i] + bv;
            y[c][i] = v;
            sm[i] += v;
            sq[i] += v * v;
        }
    }
#pragma unroll
    for (int off = 1; off < 16; off <<= 1) {
#pragma unroll
        for (int i = 0; i < 4; ++i) {
            sm[i] += __shfl_xor(sm[i], off);
            sq[i] += __shfl_xor(sq[i], off);
        }
    }
    float mean[4], rstd[4];
#pragma unroll
    for (int i = 0; i < 4; ++i) {
        mean[i] = sm[i] * (1.0f / H);
        float var = sq[i] * (1.0f / H) - mean[i] * mean[i];
        rstd[i] = rsqrtf(var + LN_EPS);
    }
    float gv[8], bbv[8];
#pragma unroll
    for (int c = 0; c < 8; ++c) { gv[c] = g[c * 16 + s]; bbv[c] = bb[c * 16 + s]; }

    __syncthreads();
#pragma unroll
    for (int i = 0; i < 4; ++i) {
        int lr = wave * 16 + quad * 4 + i;
#pragma unroll
        for (int c = 0; c < 8; ++c) {
            float yv = (y[c][i] - mean[i]) * rstd[i] * gv[c] + bbv[c];
            yv = yv > 0.f ? yv : expf(yv) - 1.f;
            As[lr * APAD + c * 16 + s] = __float2half(yv);
        }
    }
    __syncthreads();
#pragma unroll
    for (int it = 0; it < 4; ++it) {
        int idx = tid + it * 256;
        int r = idx >> 4, ch = idx & 15;
        int grow = row0 + r;
        if (grow < N_NODES) {
            float4 sv = *(float4*)(&As[r * APAD + ch * 8]);
            float4 hv = *(const float4*)(hin + (size_t)grow * H + ch * 8);
            __half2* pa = (__half2*)&sv;
            const __half2* pb = (const __half2*)&hv;
#pragma unroll
            for (int j = 0; j < 4; ++j) {
                float2 fa = __half22float2(pa[j]);
                float2 fb = __half22float2(pb[j]);
                pa[j] = __floats2half2_rn(fa.x + fb.x, fa.y + fb.y);
            }
            *(float4*)(hout + (size_t)grow * H + ch * 8) = sv;
        }
    }
}

// ---------- MFMA gate (LDS-B) ----------
__global__ __launch_bounds__(256) void k_gate_mfma(const __half* __restrict__ h16,
                                                   const __half* __restrict__ W16g,
                                                   const float* __restrict__ b1,
                                                   const float* __restrict__ w2,
                                                   const float* __restrict__ b2,
                                                   float* __restrict__ gate) {
    __shared__ __half Bs[64 * BPAD];
    int tid = threadIdx.x;
    int wave = tid >> 6, lane = tid & 63;
    int s = lane & 15, quad = lane >> 4;
    int row0 = blockIdx.x * 64 + wave * 16;
    int arow = row0 + s;
    if (arow >= N_NODES) arow = N_NODES - 1;

#pragma unroll
    for (int it = 0; it < 4; ++it) {
        int idx = tid + it * 256;
        int n = idx >> 4, ch = idx & 15;
        *(float4*)(&Bs[n * BPAD + ch * 8]) = *(const float4*)(W16g + (size_t)n * 128 + ch * 8);
    }
    __syncthreads();

    f32x4 acc[4];
#pragma unroll
    for (int c = 0; c < 4; ++c) acc[c] = (f32x4){0.f, 0.f, 0.f, 0.f};

    const __half* aptr = h16 + (size_t)arow * H;
#pragma unroll
    for (int kc = 0; kc < 128; kc += 32) {
        f16x8 afrag = *(const f16x8*)(aptr + kc + quad * 8);
#pragma unroll
        for (int c = 0; c < 4; ++c) {
            f16x8 bfrag = *(const f16x8*)(&Bs[(c * 16 + s) * BPAD + kc + quad * 8]);
            acc[c] = __builtin_amdgcn_mfma_f32_16x16x32_f16(afrag, bfrag, acc[c], 0, 0, 0);
        }
    }
    float part[4] = {0.f, 0.f, 0.f, 0.f};
#pragma unroll
    for (int c = 0; c < 4; ++c) {
        float bv = b1[c * 16 + s];
        float wv = w2[c * 16 + s];
#pragma unroll
        for (int i = 0; i < 4; ++i)
            part[i] += fmaxf(acc[c][i] + bv, 0.f) * wv;
    }
#pragma unroll
    for (int off = 1; off < 16; off <<= 1) {
#pragma unroll
        for (int i = 0; i < 4; ++i) part[i] += __shfl_xor(part[i], off);
    }
    if (s == 0) {
        float b2v = b2[0];
#pragma unroll
        for (int i = 0; i < 4; ++i) {
            int r = row0 + quad * 4 + i;
            if (r < N_NODES) gate[r] = part[i] + b2v;
        }
    }
}

// ---------- per-graph softmax over sorted batch ----------
__global__ __launch_bounds__(64) void k_softmax_g(float* __restrict__ gate,
                                                  const int* __restrict__ batch32,
                                                  float* __restrict__ gsum) {
    int g = blockIdx.x;
    int lane = threadIdx.x;
    int n0 = lower_bound(batch32, N_NODES, g);
    int n1 = lower_bound(batch32, N_NODES, g + 1);
    float m = -INFINITY;
    for (int n = n0 + lane; n < n1; n += 64) m = fmaxf(m, gate[n]);
#pragma unroll
    for (int off = 32; off >= 1; off >>= 1) m = fmaxf(m, __shfl_xor(m, off));
    float s = 0.f;
    for (int n = n0 + lane; n < n1; n += 64) {
        float e = expf(gate[n] - m);
        gate[n] = e;
        s += e;
    }
#pragma unroll
    for (int off = 32; off >= 1; off >>= 1) s += __shfl_xor(s, off);
    if (lane == 0) gsum[g] = s;
}

// ---------- per-graph pooling (no atomics) ----------
__global__ __launch_bounds__(256) void k_pool_g(const __half* __restrict__ h16,
                                                const float* __restrict__ eg,
                                                const float* __restrict__ gsum,
                                                const int* __restrict__ batch32,
                                                float* __restrict__ pooled) {
    __shared__ float sacc[256];
    int g = blockIdx.x;
    int tid = threadIdx.x;
    int c = tid & 127;
    int p = tid >> 7;
    int n0 = lower_bound(batch32, N_NODES, g);
    int n1 = lower_bound(batch32, N_NODES, g + 1);
    float acc = 0.f;
    for (int n = n0 + p; n < n1; n += 2)
        acc += eg[n] * __half2float(h16[(size_t)n * H + c]);
    sacc[tid] = acc;
    __syncthreads();
    if (tid < 128) {
        float s = gsum[g];
        float v = sacc[tid] + sacc[tid + 128];
        pooled[(size_t)g * H + tid] = (n1 > n0) ? v / s : 0.f;
    }
}

// ---------- classifier ----------
__global__ __launch_bounds__(64) void k_cls(const float* __restrict__ pooled,
                                            const float* __restrict__ w1,
                                            const float* __restrict__ b1,
                                            const float* __restrict__ w2,
                                            const float* __restrict__ b2,
                                            float* __restrict__ out) {
    __shared__ float sp[64];
    int g = blockIdx.x;
    int lane = threadIdx.x;
    float r0 = pooled[(size_t)g * H + lane];
    float r1 = pooled[(size_t)g * H + 64 + lane];
    float acc = b1[lane];
#pragma unroll 16
    for (int k = 0; k < 64; ++k) acc += __shfl(r0, k) * w1[k * 64 + lane];
#pragma unroll 16
    for (int k = 0; k < 64; ++k) acc += __shfl(r1, k) * w1[(64 + k) * 64 + lane];
    sp[lane] = fmaxf(acc, 0.f);
    __syncthreads();
    if (lane < NUM_CLASSES) {
        float o = b2[lane];
        for (int c = 0; c < 64; ++c) o += sp[c] * w2[c * NUM_CLASSES + lane];
        out[g * NUM_CLASSES + lane] = o;
    }
}

extern "C" void kernel_launch(void* const* d_in, const int* in_sizes, int n_in,
                              void* d_out, int out_size, void* d_ws, size_t ws_size,
                              hipStream_t stream) {
    const float* x       = (const float*)d_in[0];
    const int*   eraw    = (const int*)d_in[1];
    const int*   braw    = (const int*)d_in[2];
    const float* proj_w  = (const float*)d_in[3];
    const float* proj_b  = (const float*)d_in[4];
    const float* lin_l_w = (const float*)d_in[5];
    const float* lin_l_b = (const float*)d_in[6];
    const float* lin_r_w = (const float*)d_in[7];
    const float* ln_g    = (const float*)d_in[8];
    const float* ln_b    = (const float*)d_in[9];
    const float* gate_w1 = (const float*)d_in[10];
    const float* gate_b1 = (const float*)d_in[11];
    const float* gate_w2 = (const float*)d_in[12];
    const float* gate_b2 = (const float*)d_in[13];
    const float* cls_w1  = (const float*)d_in[14];
    const float* cls_b1  = (const float*)d_in[15];
    const float* cls_w2  = (const float*)d_in[16];
    const float* cls_b2  = (const float*)d_in[17];
    float* out = (float*)d_out;

    // workspace layout: ping-pong node-feature buffers
    __half* hA     = (__half*)d_ws;                       // N*H f16
    __half* hB     = hA + (size_t)N_NODES * H;            // N*H f16
    float*  gate   = (float*)(hB + (size_t)N_NODES * H);  // N
    float*  gsum   = gate + N_NODES;                      // 512
    float*  pooled = gsum + NUM_GRAPHS;                   // 512*H
    __half* W16t   = (__half*)(pooled + NUM_GRAPHS * H);  // 3*128*256
    __half* W16g   = W16t + (size_t)NUM_LAYERS * 32768;   // 64*128
    int* flags     = (int*)(W16g + 64 * 128);             // 4
    int* col       = flags + 4;                           // E
    int* batch32   = col + N_EDGES;                       // N
    int* deg       = batch32 + N_NODES;                   // N
    int* rowptr    = deg + N_NODES;                       // N+1
    int* cursor    = rowptr + N_NODES + 1;                // N
    int* bsums     = cursor + N_NODES;                    // 256
    int* bcnt      = bsums + 256;                         // 512
    int* boff      = bcnt + 512;                          // 513
    int* bcursor   = boff + 513;                          // 512
    unsigned int* br = (unsigned int*)(bcursor + 512);    // E packed records

    const int nbN = (N_NODES + 255) / 256;
    const int nbE4 = (N_EDGES + EPB - 1) / EPB;           // 391
    const int nbS = (N_NODES + 511) / 512;                // 196
    const int nbG = (N_NODES + 63) / 64;                  // 1563
    const int nbP = (NUM_LAYERS * 128 * 256 + 64 * 128 + 255) / 256;

    k_detect<<<1, 1, 0, stream>>>(eraw, braw, flags);
    k_init<<<2, 256, 0, stream>>>(bcnt);
    k_conv_batch<<<nbN, 256, 0, stream>>>(braw, flags, batch32);
    // CSR build (bucketed)
    k_bhist<<<512, 256, 0, stream>>>(eraw, flags, bcnt);
    k_bscan<<<1, 512, 0, stream>>>(bcnt, boff, bcursor);
    k_bucket<<<nbE4, 256, 0, stream>>>(eraw, flags, bcursor, br);
    k_bdeg<<<NBKT, 256, 0, stream>>>(br, boff, deg);
    k_scan1<<<nbS, 256, 0, stream>>>(deg, rowptr, bsums);
    k_scan2<<<1, 256, 0, stream>>>(bsums, nbS);
    k_scan3<<<nbN, 256, 0, stream>>>(rowptr, bsums, cursor);
    k_scatter2<<<NBKT, 256, 0, stream>>>(br, boff, rowptr, cursor, col);
    // weights to fp16 transposed
    k_prepw<<<nbP, 256, 0, stream>>>(lin_l_w, lin_r_w, gate_w1, W16t, W16g);

    // hA = fp16(relu(x @ proj_w + proj_b))
    k_gemm_proj<<<nbG, 256, 0, stream>>>(x, proj_w, proj_b, hA, N_NODES, NDIM);

    __half* hin = hA;
    __half* hout = hB;
    for (int l = 0; l < NUM_LAYERS; ++l) {
        const float* bl  = lin_l_b + (size_t)l * H;
        const float* gl  = ln_g + (size_t)l * H;
        const float* blb = ln_b + (size_t)l * H;
        k_aggr_layer<<<nbG, 256, 0, stream>>>(hin, hout, rowptr, col,
                                              W16t + (size_t)l * 32768, bl, gl, blb);
        __half* tmp = hin; hin = hout; hout = tmp;
    }
    __half* hfin = hin;   // final features after the swap

    // gate -> per-graph softmax -> per-graph pooling -> classifier
    k_gate_mfma<<<nbG, 256, 0, stream>>>(hfin, W16g, gate_b1, gate_w2, gate_b2, gate);
    k_softmax_g<<<NUM_GRAPHS, 64, 0, stream>>>(gate, batch32, gsum);
    k_pool_g<<<NUM_GRAPHS, 256, 0, stream>>>(hfin, gate, gsum, batch32, pooled);
    k_cls<<<NUM_GRAPHS, 64, 0, stream>>>(pooled, cls_w1, cls_b1, cls_w2, cls_b2, out);
}

// Round 12
// 498.178 us; speedup vs baseline: 1.4633x; 1.4633x over previous
//
#include <hip/hip_runtime.h>
#include <hip/hip_fp16.h>
#include <math.h>

#define N_NODES   100000
#define N_EDGES   1600000
#define NDIM      64
#define H         128
#define NUM_LAYERS 3
#define NUM_CLASSES 6
#define NUM_GRAPHS 512
#define LN_EPS    1e-5f
#define NBKT      391           // ceil(N_NODES / 256)
#define SCAP      5376          // CSR-tail LDS col capacity (bucket mean 4092, std 64)
#define BPAD      136           // LDS row stride (halves)

typedef _Float16 f16x8 __attribute__((ext_vector_type(8)));
typedef float    f32x4 __attribute__((ext_vector_type(4)));

// ---------- helpers ----------
__device__ __forceinline__ int idx_at(const int* raw, int is64, int i) {
    return is64 ? raw[2 * (long long)i] : raw[i];
}
__device__ __forceinline__ int lower_bound(const int* a, int n, int v) {
    int lo = 0, hi = n;
    while (lo < hi) { int m = (lo + hi) >> 1; if (a[m] < v) lo = m + 1; else hi = m; }
    return lo;
}

// ---------- dtype detection ----------
__global__ void k_detect(const int* eraw, const int* braw, int* flags) {
    if (threadIdx.x == 0 && blockIdx.x == 0) {
        int e64 = 1;
        for (int i = 1; i < 128; i += 2) if (eraw[i] != 0) { e64 = 0; break; }
        flags[0] = e64;
        flags[1] = (braw[N_NODES - 1] == 0) ? 1 : 0;
    }
}

// ---------- init ----------
__global__ void k_init(int* bcnt) {
    int i = blockIdx.x * blockDim.x + threadIdx.x;
    if (i < 512) bcnt[i] = 0;
}

__global__ void k_conv_batch(const int* braw, const int* flags, int* batch32) {
    int i = blockIdx.x * blockDim.x + threadIdx.x;
    if (i < N_NODES) batch32[i] = idx_at(braw, flags[1], i);
}

// ---------- bucket histogram (512 buckets by dst>>8), LDS-aggregated ----------
__global__ __launch_bounds__(256) void k_bhist(const int* eraw, const int* flags, int* bcnt) {
    __shared__ int c[512];
    int tid = threadIdx.x;
    for (int i = tid; i < 512; i += 256) c[i] = 0;
    __syncthreads();
    int f = flags[0];
    int stride = gridDim.x * 256;
    for (int e = blockIdx.x * 256 + tid; e < N_EDGES; e += stride) {
        int d = idx_at(eraw, f, N_EDGES + e);
        atomicAdd(&c[d >> 8], 1);
    }
    __syncthreads();
    for (int i = tid; i < 512; i += 256) if (c[i]) atomicAdd(&bcnt[i], c[i]);
}

// ---------- scan of 512 bucket counts -> boff[513], bcursor ----------
__global__ void k_bscan(const int* bcnt, int* boff, int* bcursor) {
    __shared__ int sh[512];
    int tid = threadIdx.x;     // 512 threads
    int v = bcnt[tid];
    sh[tid] = v;
    __syncthreads();
    for (int off = 1; off < 512; off <<= 1) {
        int u = (tid >= off) ? sh[tid - off] : 0;
        __syncthreads();
        sh[tid] += u;
        __syncthreads();
    }
    int excl = sh[tid] - v;
    boff[tid] = excl;
    bcursor[tid] = excl;
    if (tid == 511) boff[512] = sh[511];
}

// ---------- phase A: scatter packed records into bucket-contiguous regions ----------
#define EPB 4096
__global__ __launch_bounds__(256) void k_bucket(const int* eraw, const int* flags,
                                                int* bcursor, unsigned int* br) {
    __shared__ int cnt[512];
    __shared__ int lcur[512];
    int tid = threadIdx.x;
    int f = flags[0];
    int base = blockIdx.x * EPB;
    int se[16], de[16];
#pragma unroll
    for (int j = 0; j < 16; ++j) {
        int e = base + j * 256 + tid;
        if (e < N_EDGES) {
            se[j] = idx_at(eraw, f, e);
            de[j] = idx_at(eraw, f, N_EDGES + e);
        } else de[j] = -1;
    }
    for (int i = tid; i < 512; i += 256) cnt[i] = 0;
    __syncthreads();
#pragma unroll
    for (int j = 0; j < 16; ++j)
        if (de[j] >= 0) atomicAdd(&cnt[de[j] >> 8], 1);
    __syncthreads();
    for (int i = tid; i < 512; i += 256)
        lcur[i] = cnt[i] ? atomicAdd(&bcursor[i], cnt[i]) : 0;
    __syncthreads();
#pragma unroll
    for (int j = 0; j < 16; ++j)
        if (de[j] >= 0) {
            int pos = atomicAdd(&lcur[de[j] >> 8], 1);
            br[pos] = ((unsigned int)(de[j] & 255) << 24) | (unsigned int)se[j];
        }
}

// ---------- FUSED CSR tail: per-bucket deg count + intra-bucket scan -> rowptr,
// then LDS fine-scatter -> coalesced col writeout (byte offsets src*256).
// Valid because buckets partition nodes in order: rowptr[node] = boff[b] + intra-prefix.
__global__ __launch_bounds__(256) void k_csr_tail(const unsigned int* br, const int* boff,
                                                  int* rowptr, int* col) {
    __shared__ int d256[256];
    __shared__ int sc[256];
    __shared__ int cbuf[SCAP];
    int b = blockIdx.x;
    int tid = threadIdx.x;
    int lo = boff[b], hi = boff[b + 1];
    int wsize = hi - lo;
    d256[tid] = 0;
    __syncthreads();
    for (int i = lo + tid; i < hi; i += 256)
        atomicAdd(&d256[br[i] >> 24], 1);
    __syncthreads();
    int v = d256[tid];
    sc[tid] = v;
    __syncthreads();
    for (int off = 1; off < 256; off <<= 1) {
        int u = (tid >= off) ? sc[tid - off] : 0;
        __syncthreads();
        sc[tid] += u;
        __syncthreads();
    }
    int excl = sc[tid] - v;           // intra-bucket exclusive prefix
    int node = (b << 8) + tid;
    if (node < N_NODES) rowptr[node] = lo + excl;
    if (b == NBKT - 1 && tid == 0) rowptr[N_NODES] = N_EDGES;
    __syncthreads();
    d256[tid] = excl;                 // reuse as local cursor
    __syncthreads();
    if (wsize <= SCAP) {
        for (int i = lo + tid; i < hi; i += 256) {
            unsigned int r = br[i];
            int p = atomicAdd(&d256[r >> 24], 1);
            cbuf[p] = (int)(r & 0xFFFFFF);
        }
        __syncthreads();
        for (int j = tid; j < wsize; j += 256) col[lo + j] = cbuf[j] << 8;
    } else {
        for (int i = lo + tid; i < hi; i += 256) {
            unsigned int r = br[i];
            int p = atomicAdd(&d256[r >> 24], 1);
            col[lo + p] = (int)(r & 0xFFFFFF) << 8;
        }
    }
}

// ---------- weight prep ----------
__global__ void k_prepw(const float* __restrict__ lin_l_w, const float* __restrict__ lin_r_w,
                        const float* __restrict__ gate_w1,
                        __half* __restrict__ W16t, __half* __restrict__ W16g) {
    int i = blockIdx.x * 256 + threadIdx.x;
    if (i < NUM_LAYERS * 128 * 256) {
        int l = i >> 15;
        int rem = i & 32767;
        int n = rem >> 8;
        int k = rem & 255;
        float v = (k < 128) ? lin_l_w[(size_t)l * 16384 + k * 128 + n]
                            : lin_r_w[(size_t)l * 16384 + (k - 128) * 128 + n];
        W16t[(size_t)l * 32768 + n * 256 + k] = __float2half(v);
    } else if (i < NUM_LAYERS * 128 * 256 + 64 * 128) {
        int idx = i - NUM_LAYERS * 128 * 256;
        int n = idx >> 7;
        int k = idx & 127;
        W16g[n * 128 + k] = __float2half(gate_w1[k * 64 + n]);
    }
}

// ---------- tiled fp32 GEMM (COLS=128): h16 = fp16(relu(A[n,K] @ W + bias)) ----------
__global__ __launch_bounds__(256) void k_gemm_proj(const float* __restrict__ A,
                                                   const float* __restrict__ W,
                                                   const float* __restrict__ bias,
                                                   __half* __restrict__ C16,
                                                   int nrows, int K) {
    __shared__ float As_t[32][68];
    __shared__ float Ws[32 * 128];
    int tid = threadIdx.x;
    int row0 = blockIdx.x * 64;
    int tr = tid >> 4;
    int tc = tid & 15;
    int c0 = tc * 8;
    float acc[4][8];
#pragma unroll
    for (int i = 0; i < 4; ++i)
#pragma unroll
        for (int j = 0; j < 8; ++j) acc[i][j] = 0.f;

    for (int kc = 0; kc < K; kc += 32) {
        __syncthreads();
#pragma unroll
        for (int it = 0; it < 2; ++it) {
            int idx = tid + it * 256;
            int r = idx >> 3, c4 = idx & 7;
            int gr = row0 + r;
            float4 v = make_float4(0.f, 0.f, 0.f, 0.f);
            if (gr < nrows) v = *(const float4*)(A + (size_t)gr * K + kc + c4 * 4);
            As_t[c4 * 4 + 0][r] = v.x;
            As_t[c4 * 4 + 1][r] = v.y;
            As_t[c4 * 4 + 2][r] = v.z;
            As_t[c4 * 4 + 3][r] = v.w;
        }
#pragma unroll
        for (int it = 0; it < 4; ++it) {
            int idx = tid + it * 256;
            int r = idx >> 5, c4 = idx & 31;
            *(float4*)(&Ws[r * 128 + c4 * 4]) = *(const float4*)(W + (size_t)(kc + r) * 128 + c4 * 4);
        }
        __syncthreads();
#pragma unroll
        for (int k = 0; k < 32; ++k) {
            float4 a4 = *(const float4*)(&As_t[k][tr * 4]);
            float a[4] = {a4.x, a4.y, a4.z, a4.w};
            float4 w0 = *(const float4*)(&Ws[k * 128 + c0]);
            float4 w1 = *(const float4*)(&Ws[k * 128 + c0 + 4]);
            float w[8] = {w0.x, w0.y, w0.z, w0.w, w1.x, w1.y, w1.z, w1.w};
#pragma unroll
            for (int i = 0; i < 4; ++i)
#pragma unroll
                for (int j = 0; j < 8; ++j) acc[i][j] += a[i] * w[j];
        }
    }
    float bv[8];
#pragma unroll
    for (int j = 0; j < 8; ++j) bv[j] = bias[c0 + j];
#pragma unroll
    for (int i = 0; i < 4; ++i) {
        int gr = row0 + tr * 4 + i;
        if (gr < nrows) {
            float o[8];
#pragma unroll
            for (int j = 0; j < 8; ++j) o[j] = fmaxf(acc[i][j] + bv[j], 0.f);
            __half2 p[4];
#pragma unroll
            for (int j = 0; j < 8; j += 2) p[j / 2] = __floats2half2_rn(o[j], o[j + 1]);
            *(float4*)(C16 + (size_t)gr * 128 + c0) = *(float4*)p;
        }
    }
}

// ---------- MFMA gate (LDS-B): gate[n] = relu(h16[n,:]@W16g^T + b1) . w2 + b2 ----------
__global__ __launch_bounds__(256) void k_gate_mfma(const __half* __restrict__ h16,
                                                   const __half* __restrict__ W16g,
                                                   const float* __restrict__ b1,
                                                   const float* __restrict__ w2,
                                                   const float* __restrict__ b2,
                                                   float* __restrict__ gate) {
    __shared__ __half Bs[64 * BPAD];
    int tid = threadIdx.x;
    int wave = tid >> 6, lane = tid & 63;
    int s = lane & 15, quad = lane >> 4;
    int row0 = blockIdx.x * 64 + wave * 16;
    int arow = row0 + s;
    if (arow >= N_NODES) arow = N_NODES - 1;

#pragma unroll
    for (int it = 0; it < 4; ++it) {
        int idx = tid + it * 256;
        int n = idx >> 4, ch = idx & 15;
        *(float4*)(&Bs[n * BPAD + ch * 8]) = *(const float4*)(W16g + (size_t)n * 128 + ch * 8);
    }
    __syncthreads();

    f32x4 acc[4];
#pragma unroll
    for (int c = 0; c < 4; ++c) acc[c] = (f32x4){0.f, 0.f, 0.f, 0.f};

    const __half* aptr = h16 + (size_t)arow * H;
#pragma unroll
    for (int kc = 0; kc < 128; kc += 32) {
        f16x8 afrag = *(const f16x8*)(aptr + kc + quad * 8);
#pragma unroll
        for (int c = 0; c < 4; ++c) {
            f16x8 bfrag = *(const f16x8*)(&Bs[(c * 16 + s) * BPAD + kc + quad * 8]);
            acc[c] = __builtin_amdgcn_mfma_f32_16x16x32_f16(afrag, bfrag, acc[c], 0, 0, 0);
        }
    }
    float part[4] = {0.f, 0.f, 0.f, 0.f};
#pragma unroll
    for (int c = 0; c < 4; ++c) {
        float bv = b1[c * 16 + s];
        float wv = w2[c * 16 + s];
#pragma unroll
        for (int i = 0; i < 4; ++i)
            part[i] += fmaxf(acc[c][i] + bv, 0.f) * wv;
    }
#pragma unroll
    for (int off = 1; off < 16; off <<= 1) {
#pragma unroll
        for (int i = 0; i < 4; ++i) part[i] += __shfl_xor(part[i], off);
    }
    if (s == 0) {
        float b2v = b2[0];
#pragma unroll
        for (int i = 0; i < 4; ++i) {
            int r = row0 + quad * 4 + i;
            if (r < N_NODES) gate[r] = part[i] + b2v;
        }
    }
}

// ---------- per-graph softmax over sorted batch ----------
__global__ __launch_bounds__(64) void k_softmax_g(float* __restrict__ gate,
                                                  const int* __restrict__ batch32,
                                                  float* __restrict__ gsum) {
    int g = blockIdx.x;
    int lane = threadIdx.x;
    int n0 = lower_bound(batch32, N_NODES, g);
    int n1 = lower_bound(batch32, N_NODES, g + 1);
    float m = -INFINITY;
    for (int n = n0 + lane; n < n1; n += 64) m = fmaxf(m, gate[n]);
#pragma unroll
    for (int off = 32; off >= 1; off >>= 1) m = fmaxf(m, __shfl_xor(m, off));
    float s = 0.f;
    for (int n = n0 + lane; n < n1; n += 64) {
        float e = expf(gate[n] - m);
        gate[n] = e;
        s += e;
    }
#pragma unroll
    for (int off = 32; off >= 1; off >>= 1) s += __shfl_xor(s, off);
    if (lane == 0) gsum[g] = s;
}

// ---------- per-graph pooling (no atomics) ----------
__global__ __launch_bounds__(256) void k_pool_g(const __half* __restrict__ h16,
                                                const float* __restrict__ eg,
                                                const float* __restrict__ gsum,
                                                const int* __restrict__ batch32,
                                                float* __restrict__ pooled) {
    __shared__ float sacc[256];
    int g = blockIdx.x;
    int tid = threadIdx.x;
    int c = tid & 127;
    int p = tid >> 7;
    int n0 = lower_bound(batch32, N_NODES, g);
    int n1 = lower_bound(batch32, N_NODES, g + 1);
    float acc = 0.f;
    for (int n = n0 + p; n < n1; n += 2)
        acc += eg[n] * __half2float(h16[(size_t)n * H + c]);
    sacc[tid] = acc;
    __syncthreads();
    if (tid < 128) {
        float s = gsum[g];
        float v = sacc[tid] + sacc[tid + 128];
        pooled[(size_t)g * H + tid] = (n1 > n0) ? v / s : 0.f;
    }
}

// ---------- MFMA fused SAGE layer (LDS-B, staged epilogue; split from aggr) ----------
__global__ __launch_bounds__(256) void k_layer_mfma(const __half* __restrict__ t16,
                                                    __half* __restrict__ h16,
                                                    const __half* __restrict__ W16t,
                                                    const float* __restrict__ bl,
                                                    const float* __restrict__ g,
                                                    const float* __restrict__ bb) {
    __shared__ __half Bs[128 * BPAD];   // B-tile, then reused as output staging
    int tid = threadIdx.x;
    int wave = tid >> 6, lane = tid & 63;
    int s = lane & 15, quad = lane >> 4;
    int row0 = blockIdx.x * 64;
    int wrow0 = row0 + wave * 16;
    int arow = wrow0 + s;
    if (arow >= N_NODES) arow = N_NODES - 1;

    f32x4 acc[8];
#pragma unroll
    for (int c = 0; c < 8; ++c) acc[c] = (f32x4){0.f, 0.f, 0.f, 0.f};

#pragma unroll
    for (int ph = 0; ph < 2; ++ph) {
        __syncthreads();
#pragma unroll
        for (int it = 0; it < 8; ++it) {
            int idx = tid + it * 256;
            int n = idx >> 4, ch = idx & 15;
            *(float4*)(&Bs[n * BPAD + ch * 8]) =
                *(const float4*)(W16t + (size_t)n * 256 + ph * 128 + ch * 8);
        }
        __syncthreads();
        const __half* aptr = (ph ? h16 : t16) + (size_t)arow * H;
#pragma unroll
        for (int kk = 0; kk < 128; kk += 32) {
            f16x8 afrag = *(const f16x8*)(aptr + kk + quad * 8);
#pragma unroll
            for (int c = 0; c < 8; ++c) {
                f16x8 bfrag = *(const f16x8*)(&Bs[(c * 16 + s) * BPAD + kk + quad * 8]);
                acc[c] = __builtin_amdgcn_mfma_f32_16x16x32_f16(afrag, bfrag, acc[c], 0, 0, 0);
            }
        }
    }

    float y[8][4];
    float sm[4] = {0.f, 0.f, 0.f, 0.f}, sq[4] = {0.f, 0.f, 0.f, 0.f};
#pragma unroll
    for (int c = 0; c < 8; ++c) {
        float bv = bl[c * 16 + s];
#pragma unroll
        for (int i = 0; i < 4; ++i) {
            float v = acc[c][i] + bv;
            y[c][i] = v;
            sm[i] += v;
            sq[i] += v * v;
        }
    }
#pragma unroll
    for (int off = 1; off < 16; off <<= 1) {
#pragma unroll
        for (int i = 0; i < 4; ++i) {
            sm[i] += __shfl_xor(sm[i], off);
            sq[i] += __shfl_xor(sq[i], off);
        }
    }
    float mean[4], rstd[4];
#pragma unroll
    for (int i = 0; i < 4; ++i) {
        mean[i] = sm[i] * (1.0f / H);
        float var = sq[i] * (1.0f / H) - mean[i] * mean[i];
        rstd[i] = rsqrtf(var + LN_EPS);
    }
    float gv[8], bbv[8];
#pragma unroll
    for (int c = 0; c < 8; ++c) { gv[c] = g[c * 16 + s]; bbv[c] = bb[c * 16 + s]; }

    __syncthreads();
#pragma unroll
    for (int i = 0; i < 4; ++i) {
        int lr = wave * 16 + quad * 4 + i;
#pragma unroll
        for (int c = 0; c < 8; ++c) {
            float yv = (y[c][i] - mean[i]) * rstd[i] * gv[c] + bbv[c];
            yv = yv > 0.f ? yv : expf(yv) - 1.f;
            Bs[lr * BPAD + c * 16 + s] = __float2half(yv);
        }
    }
    __syncthreads();
#pragma unroll
    for (int it = 0; it < 4; ++it) {
        int idx = tid + it * 256;
        int r = idx >> 4, ch = idx & 15;
        int grow = row0 + r;
        if (grow < N_NODES) {
            float4 sv = *(float4*)(&Bs[r * BPAD + ch * 8]);
            float4 hv = *(const float4*)(h16 + (size_t)grow * H + ch * 8);
            __half2* pa = (__half2*)&sv;
            const __half2* pb = (const __half2*)&hv;
#pragma unroll
            for (int j = 0; j < 4; ++j) {
                float2 fa = __half22float2(pa[j]);
                float2 fb = __half22float2(pb[j]);
                pa[j] = __floats2half2_rn(fa.x + fb.x, fa.y + fb.y);
            }
            *(float4*)(h16 + (size_t)grow * H + ch * 8) = sv;
        }
    }
}

// ---------- mean aggregation: wave/node, byte-offset col, fp16 4-stream accumulation ----------
// Standalone (24 VGPR, 0 LDS) => ~70% occupancy: essential for hiding random-gather latency.
__global__ __launch_bounds__(256) void k_aggr(const __half* __restrict__ h16,
                                              const int* __restrict__ rowptr,
                                              const int* __restrict__ col,
                                              __half* __restrict__ t16) {
    int lane = threadIdx.x & 63;
    int node = blockIdx.x * 4 + (threadIdx.x >> 6);
    if (node >= N_NODES) return;
    int li = lane & 31;       // covers cols 4li..4li+3 (8 B)
    int pg = lane >> 5;       // edge-parity group
    int e0 = rowptr[node], e1 = rowptr[node + 1];
    const char* hbase = (const char*)h16 + li * 8;
    __half2 z = __floats2half2_rn(0.f, 0.f);
    __half2 a0 = z, a1 = z, b0 = z, b1 = z, c0 = z, c1 = z, d0 = z, d1 = z;
    int e = e0;
    for (; e + 7 < e1; e += 8) {
        float2 rA = *(const float2*)(hbase + col[e + pg]);
        float2 rB = *(const float2*)(hbase + col[e + 2 + pg]);
        float2 rC = *(const float2*)(hbase + col[e + 4 + pg]);
        float2 rD = *(const float2*)(hbase + col[e + 6 + pg]);
        const __half2* hA = (const __half2*)&rA;
        const __half2* hB = (const __half2*)&rB;
        const __half2* hC = (const __half2*)&rC;
        const __half2* hD = (const __half2*)&rD;
        a0 = __hadd2(a0, hA[0]); a1 = __hadd2(a1, hA[1]);
        b0 = __hadd2(b0, hB[0]); b1 = __hadd2(b1, hB[1]);
        c0 = __hadd2(c0, hC[0]); c1 = __hadd2(c1, hC[1]);
        d0 = __hadd2(d0, hD[0]); d1 = __hadd2(d1, hD[1]);
    }
    for (; e + 3 < e1; e += 4) {
        float2 rA = *(const float2*)(hbase + col[e + pg]);
        float2 rB = *(const float2*)(hbase + col[e + 2 + pg]);
        const __half2* hA = (const __half2*)&rA;
        const __half2* hB = (const __half2*)&rB;
        a0 = __hadd2(a0, hA[0]); a1 = __hadd2(a1, hA[1]);
        b0 = __hadd2(b0, hB[0]); b1 = __hadd2(b1, hB[1]);
    }
    for (; e + 1 < e1; e += 2) {
        float2 rA = *(const float2*)(hbase + col[e + pg]);
        const __half2* hA = (const __half2*)&rA;
        a0 = __hadd2(a0, hA[0]); a1 = __hadd2(a1, hA[1]);
    }
    if (e < e1 && pg == 0) {
        float2 rA = *(const float2*)(hbase + col[e]);
        const __half2* hA = (const __half2*)&rA;
        a0 = __hadd2(a0, hA[0]); a1 = __hadd2(a1, hA[1]);
    }
    float2 fa0 = __half22float2(a0), fb0 = __half22float2(b0);
    float2 fc0 = __half22float2(c0), fd0 = __half22float2(d0);
    float2 fa1 = __half22float2(a1), fb1 = __half22float2(b1);
    float2 fc1 = __half22float2(c1), fd1 = __half22float2(d1);
    float s0 = fa0.x + fb0.x + fc0.x + fd0.x;
    float s1 = fa0.y + fb0.y + fc0.y + fd0.y;
    float s2 = fa1.x + fb1.x + fc1.x + fd1.x;
    float s3 = fa1.y + fb1.y + fc1.y + fd1.y;
    s0 += __shfl_xor(s0, 32);
    s1 += __shfl_xor(s1, 32);
    s2 += __shfl_xor(s2, 32);
    s3 += __shfl_xor(s3, 32);
    if (pg == 0) {
        int d = e1 - e0;
        float inv = 1.0f / (float)(d > 1 ? d : 1);
        __half2 h01 = __floats2half2_rn(s0 * inv, s1 * inv);
        __half2 h23 = __floats2half2_rn(s2 * inv, s3 * inv);
        float2 o;
        ((__half2*)&o)[0] = h01;
        ((__half2*)&o)[1] = h23;
        *(float2*)(t16 + (size_t)node * H + li * 4) = o;
    }
}

// ---------- classifier ----------
__global__ __launch_bounds__(64) void k_cls(const float* __restrict__ pooled,
                                            const float* __restrict__ w1,
                                            const float* __restrict__ b1,
                                            const float* __restrict__ w2,
                                            const float* __restrict__ b2,
                                            float* __restrict__ out) {
    __shared__ float sp[64];
    int g = blockIdx.x;
    int lane = threadIdx.x;
    float r0 = pooled[(size_t)g * H + lane];
    float r1 = pooled[(size_t)g * H + 64 + lane];
    float acc = b1[lane];
#pragma unroll 16
    for (int k = 0; k < 64; ++k) acc += __shfl(r0, k) * w1[k * 64 + lane];
#pragma unroll 16
    for (int k = 0; k < 64; ++k) acc += __shfl(r1, k) * w1[(64 + k) * 64 + lane];
    sp[lane] = fmaxf(acc, 0.f);
    __syncthreads();
    if (lane < NUM_CLASSES) {
        float o = b2[lane];
        for (int c = 0; c < 64; ++c) o += sp[c] * w2[c * NUM_CLASSES + lane];
        out[g * NUM_CLASSES + lane] = o;
    }
}

extern "C" void kernel_launch(void* const* d_in, const int* in_sizes, int n_in,
                              void* d_out, int out_size, void* d_ws, size_t ws_size,
                              hipStream_t stream) {
    const float* x       = (const float*)d_in[0];
    const int*   eraw    = (const int*)d_in[1];
    const int*   braw    = (const int*)d_in[2];
    const float* proj_w  = (const float*)d_in[3];
    const float* proj_b  = (const float*)d_in[4];
    const float* lin_l_w = (const float*)d_in[5];
    const float* lin_l_b = (const float*)d_in[6];
    const float* lin_r_w = (const float*)d_in[7];
    const float* ln_g    = (const float*)d_in[8];
    const float* ln_b    = (const float*)d_in[9];
    const float* gate_w1 = (const float*)d_in[10];
    const float* gate_b1 = (const float*)d_in[11];
    const float* gate_w2 = (const float*)d_in[12];
    const float* gate_b2 = (const float*)d_in[13];
    const float* cls_w1  = (const float*)d_in[14];
    const float* cls_b1  = (const float*)d_in[15];
    const float* cls_w2  = (const float*)d_in[16];
    const float* cls_b2  = (const float*)d_in[17];
    float* out = (float*)d_out;

    // workspace layout
    __half* h16    = (__half*)d_ws;                       // N*H f16
    __half* t16    = h16 + (size_t)N_NODES * H;           // N*H f16
    float*  gate   = (float*)(t16 + (size_t)N_NODES * H); // N
    float*  gsum   = gate + N_NODES;                      // 512
    float*  pooled = gsum + NUM_GRAPHS;                   // 512*H
    __half* W16t   = (__half*)(pooled + NUM_GRAPHS * H);  // 3*128*256
    __half* W16g   = W16t + (size_t)NUM_LAYERS * 32768;   // 64*128
    int* flags     = (int*)(W16g + 64 * 128);             // 4
    int* col       = flags + 4;                           // E
    int* batch32   = col + N_EDGES;                       // N
    int* rowptr    = batch32 + N_NODES;                   // N+1
    int* bcnt      = rowptr + N_NODES + 1;                // 512
    int* boff      = bcnt + 512;                          // 513
    int* bcursor   = boff + 513;                          // 512
    unsigned int* br = (unsigned int*)(bcursor + 512);    // E packed records

    const int nbN = (N_NODES + 255) / 256;
    const int nbE4 = (N_EDGES + EPB - 1) / EPB;           // 391
    const int nbW = (N_NODES + 3) / 4;
    const int nbG = (N_NODES + 63) / 64;                  // 1563
    const int nbP = (NUM_LAYERS * 128 * 256 + 64 * 128 + 255) / 256;

    k_detect<<<1, 1, 0, stream>>>(eraw, braw, flags);
    k_init<<<2, 256, 0, stream>>>(bcnt);
    k_conv_batch<<<nbN, 256, 0, stream>>>(braw, flags, batch32);
    // CSR build: hist -> scan -> bucket -> fused tail (deg+scan+scatter -> rowptr, col)
    k_bhist<<<512, 256, 0, stream>>>(eraw, flags, bcnt);
    k_bscan<<<1, 512, 0, stream>>>(bcnt, boff, bcursor);
    k_bucket<<<nbE4, 256, 0, stream>>>(eraw, flags, bcursor, br);
    k_csr_tail<<<NBKT, 256, 0, stream>>>(br, boff, rowptr, col);
    // weights to fp16 transposed
    k_prepw<<<nbP, 256, 0, stream>>>(lin_l_w, lin_r_w, gate_w1, W16t, W16g);

    // h16 = fp16(relu(x @ proj_w + proj_b))
    k_gemm_proj<<<nbG, 256, 0, stream>>>(x, proj_w, proj_b, h16, N_NODES, NDIM);

    for (int l = 0; l < NUM_LAYERS; ++l) {
        const float* bl  = lin_l_b + (size_t)l * H;
        const float* gl  = ln_g + (size_t)l * H;
        const float* blb = ln_b + (size_t)l * H;
        k_aggr<<<nbW, 256, 0, stream>>>(h16, rowptr, col, t16);
        k_layer_mfma<<<nbG, 256, 0, stream>>>(t16, h16, W16t + (size_t)l * 32768, bl, gl, blb);
    }

    // gate -> per-graph softmax -> per-graph pooling -> classifier
    k_gate_mfma<<<nbG, 256, 0, stream>>>(h16, W16g, gate_b1, gate_w2, gate_b2, gate);
    k_softmax_g<<<NUM_GRAPHS, 64, 0, stream>>>(gate, batch32, gsum);
    k_pool_g<<<NUM_GRAPHS, 256, 0, stream>>>(h16, gate, gsum, batch32, pooled);
    k_cls<<<NUM_GRAPHS, 64, 0, stream>>>(pooled, cls_w1, cls_b1, cls_w2, cls_b2, out);
}